// Round 10
// baseline (424.963 us; speedup 1.0000x reference)
//
#include <hip/hip_runtime.h>
#include <hip/hip_bf16.h>

typedef __attribute__((ext_vector_type(8))) short short8;
typedef __attribute__((ext_vector_type(4))) float f32x4;

#define SQ 3072
#define DM 2048
#define NHEAD 16
#define HDIM 128

__device__ __forceinline__ unsigned short f2bf(float f) {
  union { float f; unsigned int u; } un; un.f = f;
  unsigned int r = un.u + 0x7fffu + ((un.u >> 16) & 1u);
  return (unsigned short)(r >> 16);
}

// hardware cvt (RNE) — compiler lowers to v_cvt_pk_bf16_f32 / single cvt
__device__ __forceinline__ unsigned short f2bf_hw(float f) {
  __hip_bfloat16 h = __float2bfloat16(f);
  return *reinterpret_cast<unsigned short*>(&h);
}

__device__ __forceinline__ void gload_lds16(const void* g, void* l) {
  __builtin_amdgcn_global_load_lds(
      (const __attribute__((address_space(1))) void*)g,
      (__attribute__((address_space(3))) void*)l, 16, 0, 0);
}

// ---------------- fused f32 -> bf16 convert (x, Wq, Wk, Wv, Wo) ----------------
__global__ __launch_bounds__(256) void cvt_all(
    const float* __restrict__ x, const float* __restrict__ wq, const float* __restrict__ wk,
    const float* __restrict__ wv, const float* __restrict__ wo,
    unsigned short* __restrict__ xb, unsigned short* __restrict__ wqkvb,
    unsigned short* __restrict__ wob)
{
  int b = blockIdx.x;
  const float* src; unsigned short* dst; int idx;
  if (b < 3072) { src = x; dst = xb; idx = b; }
  else {
    int r = b - 3072; int w = r >> 11; idx = r & 2047;
    src = (w == 0) ? wq : (w == 1) ? wk : (w == 2) ? wv : wo;
    dst = (w < 3) ? wqkvb + (size_t)w * DM * DM : wob;
  }
  int i = (idx * 256 + threadIdx.x) * 8;
  float4 a = *(const float4*)(src + i);
  float4 c = *(const float4*)(src + i + 4);
  short8 r;
  r[0] = (short)f2bf(a.x); r[1] = (short)f2bf(a.y);
  r[2] = (short)f2bf(a.z); r[3] = (short)f2bf(a.w);
  r[4] = (short)f2bf(c.x); r[5] = (short)f2bf(c.y);
  r[6] = (short)f2bf(c.z); r[7] = (short)f2bf(c.w);
  *(short8*)(dst + i) = r;
}

// ---------------- bf16 NT GEMM + bias -> f32 -----------------------------------
// BM=128 x BN=256 tile, 512 thr (8 waves, 2m x 4n, 64x64/wave), BK=32,
// 3-buffer LDS ring (72 KB -> 2 blocks/CU), counted vmcnt(3) steady state,
// T2 swizzle, T5 setprio, T1 bijective XCD grid swizzle.
__global__ __launch_bounds__(512, 2) void gemm_nt_bias(
    const unsigned short* __restrict__ A, const unsigned short* __restrict__ B,
    const float* __restrict__ b0, const float* __restrict__ b1, const float* __restrict__ b2,
    float* __restrict__ C, int M, int N, int K, int nbm)
{
  __shared__ __align__(16) unsigned short lds[3 * 12288];
  const int tid = threadIdx.x;
  const int w = tid >> 6, l = tid & 63;
  const int wm = w >> 2, wn = w & 3;
  const int lr = l & 15, lg = l >> 4;

  const int nwg = gridDim.x;
  const int swz = (blockIdx.x & 7) * (nwg >> 3) + (blockIdx.x >> 3);
  const int m0 = (swz % nbm) * 128, n0 = (swz / nbm) * 256;

  const int srow = tid >> 2;
  const int scol = ((tid & 3) ^ ((tid >> 3) & 3)) * 8;
  const unsigned short* aS  = A + (size_t)(m0 + srow) * K + scol;
  const unsigned short* bS0 = B + (size_t)(n0 + srow) * K + scol;
  const unsigned short* bS1 = B + (size_t)(n0 + 128 + srow) * K + scol;
  const int ldst = w * 512;

  auto stage = [&](int t, int b) {
    unsigned short* base = &lds[b * 12288];
    const size_t tc = (size_t)t * 32;
    gload_lds16(aS + tc, base + ldst);
    gload_lds16(bS0 + tc, base + 4096 + ldst);
    gload_lds16(bS1 + tc, base + 8192 + ldst);
  };

  const int sx = ((lr >> 1) & 3);
  const int aoff = (wm * 64 + lr) * 32 + ((lg ^ sx) * 8);
  const int boff = 4096 + (wn * 64 + lr) * 32 + ((lg ^ sx) * 8);

  f32x4 acc[4][4] = {};
  const int nt = K >> 5;

  stage(0, 0); stage(1, 1);
  asm volatile("s_waitcnt vmcnt(3)" ::: "memory");
  __builtin_amdgcn_s_barrier();

  for (int t = 0; t < nt; ++t) {
    const unsigned short* buf = &lds[(t % 3) * 12288];
    if (t + 2 < nt) stage(t + 2, (t + 2) % 3);
    short8 af[4], bfr[4];
    #pragma unroll
    for (int m = 0; m < 4; ++m) af[m] = *(const short8*)&buf[aoff + m * 512];
    #pragma unroll
    for (int n = 0; n < 4; ++n) bfr[n] = *(const short8*)&buf[boff + n * 512];
    __builtin_amdgcn_s_setprio(1);
    #pragma unroll
    for (int m = 0; m < 4; ++m) {
      #pragma unroll
      for (int n = 0; n < 4; ++n)
        acc[m][n] = __builtin_amdgcn_mfma_f32_16x16x32_bf16(af[m], bfr[n], acc[m][n], 0, 0, 0);
    }
    __builtin_amdgcn_s_setprio(0);
    if (t + 2 < nt) {
      asm volatile("s_waitcnt vmcnt(3)" ::: "memory");
      __builtin_amdgcn_s_barrier();
    } else if (t + 2 == nt) {
      asm volatile("s_waitcnt vmcnt(0)" ::: "memory");
      __builtin_amdgcn_s_barrier();
    }
  }

  const float* bp = (n0 < DM) ? b0 : ((n0 < 2 * DM) ? b1 : b2);
  #pragma unroll
  for (int n = 0; n < 4; ++n) {
    int col = n0 + wn * 64 + n * 16 + lr;
    float bv = bp[col & (DM - 1)];
    #pragma unroll
    for (int m = 0; m < 4; ++m) {
      int row = m0 + wm * 64 + m * 16 + lg * 4;
      #pragma unroll
      for (int j = 0; j < 4; ++j)
        C[(size_t)(row + j) * N + col] = acc[m][n][j] + bv;
    }
  }
}

// ---------------- RMSNorm + RoPE + scale -> bf16 [head][S][128] ----------------
__global__ __launch_bounds__(256) void normrope(
    const float* __restrict__ qkv, const float* __restrict__ nqw, const float* __restrict__ nkw,
    const float* __restrict__ cosb, const float* __restrict__ sinb,
    unsigned short* __restrict__ Qb, unsigned short* __restrict__ Kb)
{
  const int s = blockIdx.x, z = blockIdx.y;  // z: 0=q, 1=k
  const float* row = qkv + ((size_t)s * 3 + z) * DM;
  const float* gw = z ? nkw : nqw;
  unsigned short* ob = z ? Kb : Qb;
  const int t = threadIdx.x;
  float v[8];
  {
    float4 a = *(const float4*)(row + t * 8);
    float4 b = *(const float4*)(row + t * 8 + 4);
    v[0] = a.x; v[1] = a.y; v[2] = a.z; v[3] = a.w;
    v[4] = b.x; v[5] = b.y; v[6] = b.z; v[7] = b.w;
  }
  float ss = 0.f;
  #pragma unroll
  for (int i = 0; i < 8; ++i) ss += v[i] * v[i];
  #pragma unroll
  for (int off = 1; off < 64; off <<= 1) ss += __shfl_xor(ss, off);
  __shared__ float red[4];
  const int wave = t >> 6, lane = t & 63;
  if (lane == 0) red[wave] = ss;
  __syncthreads();
  float tot = red[0] + red[1] + red[2] + red[3];
  float rsc = rsqrtf(tot * (1.0f / 2048.0f) + 1e-6f);
  const float qs = z ? 1.0f : 0.12751879522087045f;  // log2(e)/sqrt(D)
  const int col = t * 8, d = col & 127, h = col >> 7;
  const float* cb = cosb + (size_t)s * HDIM + d;
  const float* sb = sinb + (size_t)s * HDIM + d;
  float y[8];
  #pragma unroll
  for (int i = 0; i < 8; ++i) y[i] = v[i] * rsc * gw[col + i];
  short8 r;
  #pragma unroll
  for (int p = 0; p < 4; ++p) {
    float e = y[2 * p], o = y[2 * p + 1];
    float c0 = cb[2 * p], s0 = sb[2 * p];
    float c1 = cb[2 * p + 1], s1 = sb[2 * p + 1];
    r[2 * p]     = (short)f2bf((e * c0 - o * s0) * qs);
    r[2 * p + 1] = (short)f2bf((o * c1 + e * s1) * qs);
  }
  *(short8*)(ob + ((size_t)h * SQ + s) * HDIM + d) = r;
}

// ---------------- V transpose: f32 [S][ldv] -> bf16 [head][128][S] ----------------
__global__ __launch_bounds__(256) void vtrans(const float* __restrict__ V, int ldv,
                                              unsigned short* __restrict__ Vt)
{
  __shared__ float tile[64][65];
  const int db = blockIdx.x * 64, sb = blockIdx.y * 64, h = blockIdx.z;
  const int t = threadIdx.x;
  const int rr = t >> 2, c0 = (t & 3) * 16;
  const float* src = V + (size_t)(sb + rr) * ldv + h * HDIM + db + c0;
  #pragma unroll
  for (int i = 0; i < 4; ++i) {
    float4 a = *(const float4*)(src + i * 4);
    tile[rr][c0 + i * 4 + 0] = a.x; tile[rr][c0 + i * 4 + 1] = a.y;
    tile[rr][c0 + i * 4 + 2] = a.z; tile[rr][c0 + i * 4 + 3] = a.w;
  }
  __syncthreads();
  const int dr = t >> 2, s0 = (t & 3) * 16;
  short8 r0, r1;
  #pragma unroll
  for (int i = 0; i < 8; ++i) r0[i] = (short)f2bf(tile[s0 + i][dr]);
  #pragma unroll
  for (int i = 0; i < 8; ++i) r1[i] = (short)f2bf(tile[s0 + 8 + i][dr]);
  unsigned short* dst = Vt + ((size_t)h * HDIM + db + dr) * SQ + sb + s0;
  *(short8*)(dst) = r0;
  *(short8*)(dst + 8) = r1;
}

// ---------------- flash attention (no-max softmax), bf16 MFMA ----------------
// T14 async-STAGE (regs for tile t+1 issued under tile t's compute),
// Ps stride 76 (conflict-free writes+reads), hw bf16 cvt, T5 setprio.
#define PST 76
__global__ __launch_bounds__(256) void attn(
    const unsigned short* __restrict__ Qb, const unsigned short* __restrict__ Kb,
    const unsigned short* __restrict__ Vt, const int* __restrict__ seq_lens,
    unsigned short* __restrict__ aout)
{
  __shared__ __align__(16) unsigned short Ks[64 * 136];    // [64 keys][128+8 d]
  __shared__ __align__(16) unsigned short Vs[128 * 72];    // [128 d][64+8 keys]
  __shared__ __align__(16) unsigned short Ps[4][16 * PST]; // per-wave [16 q][76]
  const int tid = threadIdx.x, wave = tid >> 6, lane = tid & 63;
  const int h = blockIdx.y, q0 = blockIdx.x * 64;
  const int lr = lane & 15, lg = lane >> 4;
  const int seq_len = seq_lens[0];

  short8 qf[4];
  {
    const unsigned short* qrow = Qb + ((size_t)h * SQ + q0 + wave * 16 + lr) * HDIM;
    #pragma unroll
    for (int kk = 0; kk < 4; ++kk)
      qf[kk] = *(const short8*)(qrow + kk * 32 + lg * 8);
  }
  f32x4 o[8] = {};
  float lsum[4] = {0.f, 0.f, 0.f, 0.f};

  // staging addresses (per thread, constant across tiles)
  const unsigned short* kSrc = Kb + ((size_t)h * SQ + (tid >> 4)) * HDIM + (tid & 15) * 8;
  const unsigned short* vSrc = Vt + ((size_t)h * HDIM + (tid >> 3)) * SQ + (tid & 7) * 8;
  unsigned short* kDst = &Ks[(tid >> 4) * 136 + (tid & 15) * 8];
  unsigned short* vDst = &Vs[(tid >> 3) * 72 + (tid & 7) * 8];

  short8 kreg[4], vreg[4];
  // prologue: issue tile-0 loads (rows step 16 for K, 32 for V per chunk)
  #pragma unroll
  for (int c = 0; c < 4; ++c) {
    kreg[c] = *(const short8*)(kSrc + (size_t)c * 16 * HDIM);
    vreg[c] = *(const short8*)(vSrc + (size_t)c * 32 * SQ);
  }

  for (int kt = 0; kt < seq_len; kt += 64) {
    // write staged regs -> LDS (compiler inserts the vmcnt wait)
    #pragma unroll
    for (int c = 0; c < 4; ++c) {
      *(short8*)(kDst + c * 16 * 136) = kreg[c];
      *(short8*)(vDst + c * 32 * 72) = vreg[c];
    }
    // T14: issue NEXT tile's loads now; latency hides under this tile's compute
    if (kt + 64 < seq_len) {
      #pragma unroll
      for (int c = 0; c < 4; ++c) {
        kreg[c] = *(const short8*)(kSrc + ((size_t)(kt + 64) + c * 16) * HDIM);
        vreg[c] = *(const short8*)(vSrc + (size_t)(kt + 64) + (size_t)c * 32 * SQ);
      }
    }
    __syncthreads();

    f32x4 sf[4] = {};
    __builtin_amdgcn_s_setprio(1);
    #pragma unroll
    for (int kk = 0; kk < 4; ++kk) {
      #pragma unroll
      for (int n = 0; n < 4; ++n) {
        short8 kf = *(const short8*)&Ks[(n * 16 + lr) * 136 + kk * 32 + lg * 8];
        sf[n] = __builtin_amdgcn_mfma_f32_16x16x32_bf16(qf[kk], kf, sf[n], 0, 0, 0);
      }
    }
    __builtin_amdgcn_s_setprio(0);
    if (kt + 64 > seq_len) {
      #pragma unroll
      for (int n = 0; n < 4; ++n) {
        if (kt + n * 16 + lr >= seq_len) {
          #pragma unroll
          for (int j = 0; j < 4; ++j) sf[n][j] = -3.0e38f;
        }
      }
    }
    unsigned short* Pw = &Ps[wave][0];
    #pragma unroll
    for (int n = 0; n < 4; ++n) {
      #pragma unroll
      for (int j = 0; j < 4; ++j) {
        float p = __builtin_amdgcn_exp2f(sf[n][j]);
        lsum[j] += p;
        Pw[(lg * 4 + j) * PST + n * 16 + lr] = f2bf_hw(p);
      }
    }
    #pragma unroll
    for (int kk = 0; kk < 2; ++kk) {
      short8 pa = *(const short8*)&Pw[lr * PST + kk * 32 + lg * 8];
      __builtin_amdgcn_s_setprio(1);
      #pragma unroll
      for (int dn = 0; dn < 8; ++dn) {
        short8 vb = *(const short8*)&Vs[(dn * 16 + lr) * 72 + kk * 32 + lg * 8];
        o[dn] = __builtin_amdgcn_mfma_f32_16x16x32_bf16(pa, vb, o[dn], 0, 0, 0);
      }
      __builtin_amdgcn_s_setprio(0);
    }
    __syncthreads();
  }
  #pragma unroll
  for (int off = 1; off < 16; off <<= 1) {
    #pragma unroll
    for (int j = 0; j < 4; ++j) lsum[j] += __shfl_xor(lsum[j], off);
  }
  float rcp[4];
  #pragma unroll
  for (int j = 0; j < 4; ++j) rcp[j] = 1.0f / lsum[j];
  #pragma unroll
  for (int dn = 0; dn < 8; ++dn) {
    int col = h * HDIM + dn * 16 + lr;
    #pragma unroll
    for (int j = 0; j < 4; ++j) {
      int row = q0 + wave * 16 + lg * 4 + j;
      aout[(size_t)row * DM + col] = f2bf_hw(o[dn][j] * rcp[j]);
    }
  }
}

extern "C" void kernel_launch(void* const* d_in, const int* in_sizes, int n_in,
                              void* d_out, int out_size, void* d_ws, size_t ws_size,
                              hipStream_t stream) {
  const float* x   = (const float*)d_in[0];
  const float* Wq  = (const float*)d_in[1];
  const float* bq  = (const float*)d_in[2];
  const float* Wk  = (const float*)d_in[3];
  const float* bk  = (const float*)d_in[4];
  const float* Wv  = (const float*)d_in[5];
  const float* bv  = (const float*)d_in[6];
  const float* Wo  = (const float*)d_in[7];
  const float* bo  = (const float*)d_in[8];
  const float* nqw = (const float*)d_in[9];
  const float* nkw = (const float*)d_in[10];
  const float* rc  = (const float*)d_in[11];
  const float* rs  = (const float*)d_in[12];
  const int* seql  = (const int*)d_in[13];
  float* out = (float*)d_out;

  unsigned short* xb   = (unsigned short*)d_ws;             // S*DM bf16
  unsigned short* Wqkv = xb   + (size_t)SQ * DM;            // [3*DM][DM] bf16
  unsigned short* Wob  = Wqkv + (size_t)3 * DM * DM;
  float* qkv           = (float*)(Wob + (size_t)DM * DM);   // [S][3*DM] f32
  unsigned short* Qb   = (unsigned short*)(qkv + (size_t)3 * SQ * DM);
  unsigned short* Kb   = Qb + (size_t)SQ * DM;
  unsigned short* Vt   = Kb + (size_t)SQ * DM;
  unsigned short* aob  = Vt + (size_t)SQ * DM;              // attn out bf16 [S][DM]

  cvt_all<<<3072 + 4 * 2048, 256, 0, stream>>>(x, Wq, Wk, Wv, Wo, xb, Wqkv, Wob);

  // fused QKV GEMM: [S][3*DM] = xb * Wqkv^T  (grid 24*24 = 576 blocks)
  gemm_nt_bias<<<(SQ / 128) * (3 * DM / 256), 512, 0, stream>>>(
      xb, Wqkv, bq, bk, bv, qkv, SQ, 3 * DM, DM, SQ / 128);

  normrope<<<dim3(SQ, 2), 256, 0, stream>>>(qkv, nqw, nkw, rc, rs, Qb, Kb);
  vtrans<<<dim3(2, SQ / 64, NHEAD), 256, 0, stream>>>(qkv + 2 * DM, 3 * DM, Vt);

  attn<<<dim3(SQ / 64, NHEAD), 256, 0, stream>>>(Qb, Kb, Vt, seql, aob);

  // out-proj GEMM (grid 24*8 = 192 blocks)
  gemm_nt_bias<<<(SQ / 128) * (DM / 256), 512, 0, stream>>>(
      aob, Wob, bo, bo, bo, out, SQ, DM, DM, SQ / 128);
}

// Round 12
// 396.111 us; speedup vs baseline: 1.0728x; 1.0728x over previous
//
#include <hip/hip_runtime.h>
#include <hip/hip_bf16.h>

typedef __attribute__((ext_vector_type(8))) short short8;
typedef __attribute__((ext_vector_type(4))) float f32x4;

#define SQ 3072
#define DM 2048
#define NHEAD 16
#define HDIM 128

__device__ __forceinline__ unsigned short f2bf(float f) {
  union { float f; unsigned int u; } un; un.f = f;
  unsigned int r = un.u + 0x7fffu + ((un.u >> 16) & 1u);
  return (unsigned short)(r >> 16);
}

// hardware cvt (RNE)
__device__ __forceinline__ unsigned short f2bf_hw(float f) {
  __hip_bfloat16 h = __float2bfloat16(f);
  return *reinterpret_cast<unsigned short*>(&h);
}

__device__ __forceinline__ void gload_lds16(const void* g, void* l) {
  __builtin_amdgcn_global_load_lds(
      (const __attribute__((address_space(1))) void*)g,
      (__attribute__((address_space(3))) void*)l, 16, 0, 0);
}

// ---------------- fused f32 -> bf16 convert (x, Wq, Wk, Wv, Wo) ----------------
__global__ __launch_bounds__(256) void cvt_all(
    const float* __restrict__ x, const float* __restrict__ wq, const float* __restrict__ wk,
    const float* __restrict__ wv, const float* __restrict__ wo,
    unsigned short* __restrict__ xb, unsigned short* __restrict__ wqkvb,
    unsigned short* __restrict__ wob)
{
  int b = blockIdx.x;
  const float* src; unsigned short* dst; int idx;
  if (b < 3072) { src = x; dst = xb; idx = b; }
  else {
    int r = b - 3072; int w = r >> 11; idx = r & 2047;
    src = (w == 0) ? wq : (w == 1) ? wk : (w == 2) ? wv : wo;
    dst = (w < 3) ? wqkvb + (size_t)w * DM * DM : wob;
  }
  int i = (idx * 256 + threadIdx.x) * 8;
  float4 a = *(const float4*)(src + i);
  float4 c = *(const float4*)(src + i + 4);
  short8 r;
  r[0] = (short)f2bf(a.x); r[1] = (short)f2bf(a.y);
  r[2] = (short)f2bf(a.z); r[3] = (short)f2bf(a.w);
  r[4] = (short)f2bf(c.x); r[5] = (short)f2bf(c.y);
  r[6] = (short)f2bf(c.z); r[7] = (short)f2bf(c.w);
  *(short8*)(dst + i) = r;
}

// ---------------- bf16 NT GEMM + bias -> f32 -----------------------------------
// BM=128 x BN=256 tile, 512 thr (8 waves, 2m x 4n), BK=32, 3-buffer ring,
// counted vmcnt(3), T2 swizzle, T5 setprio, T1 XCD swizzle.
__global__ __launch_bounds__(512, 2) void gemm_nt_bias(
    const unsigned short* __restrict__ A, const unsigned short* __restrict__ B,
    const float* __restrict__ b0, const float* __restrict__ b1, const float* __restrict__ b2,
    float* __restrict__ C, int M, int N, int K, int nbm)
{
  __shared__ __align__(16) unsigned short lds[3 * 12288];
  const int tid = threadIdx.x;
  const int w = tid >> 6, l = tid & 63;
  const int wm = w >> 2, wn = w & 3;
  const int lr = l & 15, lg = l >> 4;

  const int nwg = gridDim.x;
  const int swz = (blockIdx.x & 7) * (nwg >> 3) + (blockIdx.x >> 3);
  const int m0 = (swz % nbm) * 128, n0 = (swz / nbm) * 256;

  const int srow = tid >> 2;
  const int scol = ((tid & 3) ^ ((tid >> 3) & 3)) * 8;
  const unsigned short* aS  = A + (size_t)(m0 + srow) * K + scol;
  const unsigned short* bS0 = B + (size_t)(n0 + srow) * K + scol;
  const unsigned short* bS1 = B + (size_t)(n0 + 128 + srow) * K + scol;
  const int ldst = w * 512;

  auto stage = [&](int t, int b) {
    unsigned short* base = &lds[b * 12288];
    const size_t tc = (size_t)t * 32;
    gload_lds16(aS + tc, base + ldst);
    gload_lds16(bS0 + tc, base + 4096 + ldst);
    gload_lds16(bS1 + tc, base + 8192 + ldst);
  };

  const int sx = ((lr >> 1) & 3);
  const int aoff = (wm * 64 + lr) * 32 + ((lg ^ sx) * 8);
  const int boff = 4096 + (wn * 64 + lr) * 32 + ((lg ^ sx) * 8);

  f32x4 acc[4][4] = {};
  const int nt = K >> 5;

  stage(0, 0); stage(1, 1);
  asm volatile("s_waitcnt vmcnt(3)" ::: "memory");
  __builtin_amdgcn_s_barrier();

  for (int t = 0; t < nt; ++t) {
    const unsigned short* buf = &lds[(t % 3) * 12288];
    if (t + 2 < nt) stage(t + 2, (t + 2) % 3);
    short8 af[4], bfr[4];
    #pragma unroll
    for (int m = 0; m < 4; ++m) af[m] = *(const short8*)&buf[aoff + m * 512];
    #pragma unroll
    for (int n = 0; n < 4; ++n) bfr[n] = *(const short8*)&buf[boff + n * 512];
    __builtin_amdgcn_s_setprio(1);
    #pragma unroll
    for (int m = 0; m < 4; ++m) {
      #pragma unroll
      for (int n = 0; n < 4; ++n)
        acc[m][n] = __builtin_amdgcn_mfma_f32_16x16x32_bf16(af[m], bfr[n], acc[m][n], 0, 0, 0);
    }
    __builtin_amdgcn_s_setprio(0);
    if (t + 2 < nt) {
      asm volatile("s_waitcnt vmcnt(3)" ::: "memory");
      __builtin_amdgcn_s_barrier();
    } else if (t + 2 == nt) {
      asm volatile("s_waitcnt vmcnt(0)" ::: "memory");
      __builtin_amdgcn_s_barrier();
    }
  }

  const float* bp = (n0 < DM) ? b0 : ((n0 < 2 * DM) ? b1 : b2);
  #pragma unroll
  for (int n = 0; n < 4; ++n) {
    int col = n0 + wn * 64 + n * 16 + lr;
    float bv = bp[col & (DM - 1)];
    #pragma unroll
    for (int m = 0; m < 4; ++m) {
      int row = m0 + wm * 64 + m * 16 + lg * 4;
      #pragma unroll
      for (int j = 0; j < 4; ++j)
        C[(size_t)(row + j) * N + col] = acc[m][n][j] + bv;
    }
  }
}

// ---------------- RMSNorm + RoPE + scale -> bf16 [head][S][128] ----------------
__global__ __launch_bounds__(256) void normrope(
    const float* __restrict__ qkv, const float* __restrict__ nqw, const float* __restrict__ nkw,
    const float* __restrict__ cosb, const float* __restrict__ sinb,
    unsigned short* __restrict__ Qb, unsigned short* __restrict__ Kb)
{
  const int s = blockIdx.x, z = blockIdx.y;  // z: 0=q, 1=k
  const float* row = qkv + ((size_t)s * 3 + z) * DM;
  const float* gw = z ? nkw : nqw;
  unsigned short* ob = z ? Kb : Qb;
  const int t = threadIdx.x;
  float v[8];
  {
    float4 a = *(const float4*)(row + t * 8);
    float4 b = *(const float4*)(row + t * 8 + 4);
    v[0] = a.x; v[1] = a.y; v[2] = a.z; v[3] = a.w;
    v[4] = b.x; v[5] = b.y; v[6] = b.z; v[7] = b.w;
  }
  float ss = 0.f;
  #pragma unroll
  for (int i = 0; i < 8; ++i) ss += v[i] * v[i];
  #pragma unroll
  for (int off = 1; off < 64; off <<= 1) ss += __shfl_xor(ss, off);
  __shared__ float red[4];
  const int wave = t >> 6, lane = t & 63;
  if (lane == 0) red[wave] = ss;
  __syncthreads();
  float tot = red[0] + red[1] + red[2] + red[3];
  float rsc = rsqrtf(tot * (1.0f / 2048.0f) + 1e-6f);
  const float qs = z ? 1.0f : 0.12751879522087045f;  // log2(e)/sqrt(D)
  const int col = t * 8, d = col & 127, h = col >> 7;
  const float* cb = cosb + (size_t)s * HDIM + d;
  const float* sb = sinb + (size_t)s * HDIM + d;
  float y[8];
  #pragma unroll
  for (int i = 0; i < 8; ++i) y[i] = v[i] * rsc * gw[col + i];
  short8 r;
  #pragma unroll
  for (int p = 0; p < 4; ++p) {
    float e = y[2 * p], o = y[2 * p + 1];
    float c0 = cb[2 * p], s0 = sb[2 * p];
    float c1 = cb[2 * p + 1], s1 = sb[2 * p + 1];
    r[2 * p]     = (short)f2bf((e * c0 - o * s0) * qs);
    r[2 * p + 1] = (short)f2bf((o * c1 + e * s1) * qs);
  }
  *(short8*)(ob + ((size_t)h * SQ + s) * HDIM + d) = r;
}

// ---------------- V transpose: f32 [S][ldv] -> bf16 [head][128][S] ----------------
__global__ __launch_bounds__(256) void vtrans(const float* __restrict__ V, int ldv,
                                              unsigned short* __restrict__ Vt)
{
  __shared__ float tile[64][65];
  const int db = blockIdx.x * 64, sb = blockIdx.y * 64, h = blockIdx.z;
  const int t = threadIdx.x;
  const int rr = t >> 2, c0 = (t & 3) * 16;
  const float* src = V + (size_t)(sb + rr) * ldv + h * HDIM + db + c0;
  #pragma unroll
  for (int i = 0; i < 4; ++i) {
    float4 a = *(const float4*)(src + i * 4);
    tile[rr][c0 + i * 4 + 0] = a.x; tile[rr][c0 + i * 4 + 1] = a.y;
    tile[rr][c0 + i * 4 + 2] = a.z; tile[rr][c0 + i * 4 + 3] = a.w;
  }
  __syncthreads();
  const int dr = t >> 2, s0 = (t & 3) * 16;
  short8 r0, r1;
  #pragma unroll
  for (int i = 0; i < 8; ++i) r0[i] = (short)f2bf(tile[s0 + i][dr]);
  #pragma unroll
  for (int i = 0; i < 8; ++i) r1[i] = (short)f2bf(tile[s0 + 8 + i][dr]);
  unsigned short* dst = Vt + ((size_t)h * HDIM + db + dr) * SQ + sb + s0;
  *(short8*)(dst) = r0;
  *(short8*)(dst + 8) = r1;
}

// ---------------- flash attention (no-max softmax), bf16 MFMA ----------------
// LDS-BW-bound fix: 32 q-rows/wave (2x16 subblocks) -> every K/V fragment
// ds_read feeds TWO MFMAs; per-FLOP LDS traffic halved. 128 q-rows/block.
// T14 async staging, Ps stride 76, hw cvt, T5 setprio.
#define PST 76
__global__ __launch_bounds__(256, 2) void attn(
    const unsigned short* __restrict__ Qb, const unsigned short* __restrict__ Kb,
    const unsigned short* __restrict__ Vt, const int* __restrict__ seq_lens,
    unsigned short* __restrict__ aout)
{
  __shared__ __align__(16) unsigned short Ks[64 * 136];        // [64 kv][128+8 d]
  __shared__ __align__(16) unsigned short Vs[128 * 72];        // [128 d][64+8 kv]
  __shared__ __align__(16) unsigned short Ps[4][2][16 * PST];  // [wave][sub][16 q][76]
  const int tid = threadIdx.x, wave = tid >> 6, lane = tid & 63;
  const int h = blockIdx.y, q0 = blockIdx.x * 128;
  const int lr = lane & 15, lg = lane >> 4;
  const int seq_len = seq_lens[0];

  short8 qf[2][4];
  #pragma unroll
  for (int s = 0; s < 2; ++s) {
    const unsigned short* qrow =
        Qb + ((size_t)h * SQ + q0 + wave * 32 + s * 16 + lr) * HDIM;
    #pragma unroll
    for (int kk = 0; kk < 4; ++kk)
      qf[s][kk] = *(const short8*)(qrow + kk * 32 + lg * 8);
  }
  f32x4 o[2][8] = {};
  float lsum[2][4] = {};

  const unsigned short* kSrc = Kb + ((size_t)h * SQ + (tid >> 4)) * HDIM + (tid & 15) * 8;
  const unsigned short* vSrc = Vt + ((size_t)h * HDIM + (tid >> 3)) * SQ + (tid & 7) * 8;
  unsigned short* kDst = &Ks[(tid >> 4) * 136 + (tid & 15) * 8];
  unsigned short* vDst = &Vs[(tid >> 3) * 72 + (tid & 7) * 8];

  short8 kreg[4], vreg[4];
  #pragma unroll
  for (int c = 0; c < 4; ++c) {
    kreg[c] = *(const short8*)(kSrc + (size_t)c * 16 * HDIM);
    vreg[c] = *(const short8*)(vSrc + (size_t)c * 32 * SQ);
  }

  for (int kt = 0; kt < seq_len; kt += 64) {
    #pragma unroll
    for (int c = 0; c < 4; ++c) {
      *(short8*)(kDst + c * 16 * 136) = kreg[c];
      *(short8*)(vDst + c * 32 * 72) = vreg[c];
    }
    if (kt + 64 < seq_len) {  // T14: next tile's loads hide under this compute
      #pragma unroll
      for (int c = 0; c < 4; ++c) {
        kreg[c] = *(const short8*)(kSrc + ((size_t)(kt + 64) + c * 16) * HDIM);
        vreg[c] = *(const short8*)(vSrc + (size_t)(kt + 64) + (size_t)c * 32 * SQ);
      }
    }
    __syncthreads();

    f32x4 sf[2][4] = {};
    __builtin_amdgcn_s_setprio(1);
    #pragma unroll
    for (int kk = 0; kk < 4; ++kk) {
      #pragma unroll
      for (int n = 0; n < 4; ++n) {
        short8 kf = *(const short8*)&Ks[(n * 16 + lr) * 136 + kk * 32 + lg * 8];
        sf[0][n] = __builtin_amdgcn_mfma_f32_16x16x32_bf16(qf[0][kk], kf, sf[0][n], 0, 0, 0);
        sf[1][n] = __builtin_amdgcn_mfma_f32_16x16x32_bf16(qf[1][kk], kf, sf[1][n], 0, 0, 0);
      }
    }
    __builtin_amdgcn_s_setprio(0);
    if (kt + 64 > seq_len) {
      #pragma unroll
      for (int n = 0; n < 4; ++n) {
        if (kt + n * 16 + lr >= seq_len) {
          #pragma unroll
          for (int j = 0; j < 4; ++j) { sf[0][n][j] = -3.0e38f; sf[1][n][j] = -3.0e38f; }
        }
      }
    }
    #pragma unroll
    for (int s = 0; s < 2; ++s) {
      unsigned short* Pw = &Ps[wave][s][0];
      #pragma unroll
      for (int n = 0; n < 4; ++n) {
        #pragma unroll
        for (int j = 0; j < 4; ++j) {
          float p = __builtin_amdgcn_exp2f(sf[s][n][j]);
          lsum[s][j] += p;
          Pw[(lg * 4 + j) * PST + n * 16 + lr] = f2bf_hw(p);
        }
      }
    }
    #pragma unroll
    for (int kk = 0; kk < 2; ++kk) {
      short8 pa0 = *(const short8*)&Ps[wave][0][lr * PST + kk * 32 + lg * 8];
      short8 pa1 = *(const short8*)&Ps[wave][1][lr * PST + kk * 32 + lg * 8];
      __builtin_amdgcn_s_setprio(1);
      #pragma unroll
      for (int dn = 0; dn < 8; ++dn) {
        short8 vb = *(const short8*)&Vs[(dn * 16 + lr) * 72 + kk * 32 + lg * 8];
        o[0][dn] = __builtin_amdgcn_mfma_f32_16x16x32_bf16(pa0, vb, o[0][dn], 0, 0, 0);
        o[1][dn] = __builtin_amdgcn_mfma_f32_16x16x32_bf16(pa1, vb, o[1][dn], 0, 0, 0);
      }
      __builtin_amdgcn_s_setprio(0);
    }
    __syncthreads();
  }
  #pragma unroll
  for (int off = 1; off < 16; off <<= 1) {
    #pragma unroll
    for (int s = 0; s < 2; ++s) {
      #pragma unroll
      for (int j = 0; j < 4; ++j) lsum[s][j] += __shfl_xor(lsum[s][j], off);
    }
  }
  #pragma unroll
  for (int s = 0; s < 2; ++s) {
    float rcp[4];
    #pragma unroll
    for (int j = 0; j < 4; ++j) rcp[j] = 1.0f / lsum[s][j];
    #pragma unroll
    for (int dn = 0; dn < 8; ++dn) {
      int col = h * HDIM + dn * 16 + lr;
      #pragma unroll
      for (int j = 0; j < 4; ++j) {
        int row = q0 + wave * 32 + s * 16 + lg * 4 + j;
        aout[(size_t)row * DM + col] = f2bf_hw(o[s][dn][j] * rcp[j]);
      }
    }
  }
}

extern "C" void kernel_launch(void* const* d_in, const int* in_sizes, int n_in,
                              void* d_out, int out_size, void* d_ws, size_t ws_size,
                              hipStream_t stream) {
  const float* x   = (const float*)d_in[0];
  const float* Wq  = (const float*)d_in[1];
  const float* bq  = (const float*)d_in[2];
  const float* Wk  = (const float*)d_in[3];
  const float* bk  = (const float*)d_in[4];
  const float* Wv  = (const float*)d_in[5];
  const float* bv  = (const float*)d_in[6];
  const float* Wo  = (const float*)d_in[7];
  const float* bo  = (const float*)d_in[8];
  const float* nqw = (const float*)d_in[9];
  const float* nkw = (const float*)d_in[10];
  const float* rc  = (const float*)d_in[11];
  const float* rs  = (const float*)d_in[12];
  const int* seql  = (const int*)d_in[13];
  float* out = (float*)d_out;

  unsigned short* xb   = (unsigned short*)d_ws;             // S*DM bf16
  unsigned short* Wqkv = xb   + (size_t)SQ * DM;            // [3*DM][DM] bf16
  unsigned short* Wob  = Wqkv + (size_t)3 * DM * DM;
  float* qkv           = (float*)(Wob + (size_t)DM * DM);   // [S][3*DM] f32
  unsigned short* Qb   = (unsigned short*)(qkv + (size_t)3 * SQ * DM);
  unsigned short* Kb   = Qb + (size_t)SQ * DM;
  unsigned short* Vt   = Kb + (size_t)SQ * DM;
  unsigned short* aob  = Vt + (size_t)SQ * DM;              // attn out bf16 [S][DM]

  cvt_all<<<3072 + 4 * 2048, 256, 0, stream>>>(x, Wq, Wk, Wv, Wo, xb, Wqkv, Wob);

  // fused QKV GEMM: [S][3*DM] = xb * Wqkv^T  (grid 24*24 = 576 blocks)
  gemm_nt_bias<<<(SQ / 128) * (3 * DM / 256), 512, 0, stream>>>(
      xb, Wqkv, bq, bk, bv, qkv, SQ, 3 * DM, DM, SQ / 128);

  normrope<<<dim3(SQ, 2), 256, 0, stream>>>(qkv, nqw, nkw, rc, rs, Qb, Kb);
  vtrans<<<dim3(2, SQ / 64, NHEAD), 256, 0, stream>>>(qkv + 2 * DM, 3 * DM, Vt);

  attn<<<dim3(SQ / 128, NHEAD), 256, 0, stream>>>(Qb, Kb, Vt, seql, aob);

  // out-proj GEMM (grid 24*8 = 192 blocks)
  gemm_nt_bias<<<(SQ / 128) * (DM / 256), 512, 0, stream>>>(
      aob, Wob, bo, bo, bo, out, SQ, DM, DM, SQ / 128);
}